// Round 19
// baseline (59.358 us; speedup 1.0000x reference)
//
#include <hip/hip_runtime.h>

#define BATCH 4096
#define IN_DIM 512
#define H1DIM 128
#define H2DIM 64
#define DDIM 64
#define NFUNC 2081
#define NFPAD 2112
#define CHUNK 704           // 2112 = 3 * 704
#define KS_PER_CHUNK 22     // 704/32

typedef short bf16x8 __attribute__((ext_vector_type(8)));
typedef float f32x4 __attribute__((ext_vector_type(4)));
#define MFMA(a,b,c) __builtin_amdgcn_mfma_f32_16x16x32_bf16(a,b,c,0,0,0)

#define WSZ1 (H1DIM*IN_DIM)
#define WSZ2 (H2DIM*H1DIM)
#define WSZ3 (DDIM*H2DIM)
#define WSZ4 (H2DIM*DDIM)
#define WSZ5 (H1DIM*H2DIM)
#define WSZ6 (IN_DIM*H1DIM)

__device__ __forceinline__ short f2b(float f) {
    union { float f; unsigned u; } x; x.f = f;
    unsigned r = x.u + 0x7fffu + ((x.u >> 16) & 1u);
    return (short)(r >> 16);
}
__device__ __forceinline__ float b2f(short s) {
    union { unsigned u; float f; } x; x.u = ((unsigned)(unsigned short)s) << 16;
    return x.f;
}
__device__ __forceinline__ void split3f(float v, short& s0, short& s1, short& s2) {
    s0 = f2b(v); float r = v - b2f(s0);
    s1 = f2b(r); float r2 = r - b2f(s1);
    s2 = f2b(r2);
}

// raw barrier: drains LDS (lgkm) only; global (vmcnt) queue stays in flight.
__device__ __forceinline__ void barrier_lds() {
    asm volatile("s_waitcnt lgkmcnt(0)" ::: "memory");
    __builtin_amdgcn_s_barrier();
    __builtin_amdgcn_sched_barrier(0);
}

// ---- swizzled LDS tile helpers (row stride RS shorts, byte ^= (r&7)<<4) ----
__device__ __forceinline__ void st_b16(short* t, int RS, int r, int c, short v) {
    int b = (c * 2) ^ ((r & 7) << 4);
    *(short*)((char*)(t + r * RS) + b) = v;
}
__device__ __forceinline__ void st_b32s(short* t, int RS, int r, int c, unsigned v) {
    int b = (c * 2) ^ ((r & 7) << 4);   // c even -> 4B aligned
    *(unsigned*)((char*)(t + r * RS) + b) = v;
}
// 16B store of 8 consecutive k (c0 multiple of 8 -> one swizzle block)
__device__ __forceinline__ void st_b128(short* t, int RS, int r, int c0, bf16x8 v) {
    int b = (c0 * 2) ^ ((r & 7) << 4);
    *(bf16x8*)((char*)(t + r * RS) + b) = v;
}
__device__ __forceinline__ bf16x8 ld_af(const short* t, int RS, int lane, int kbase) {
    int r = lane & 15;
    int b = ((kbase + (lane >> 4) * 8) * 2) ^ ((r & 7) << 4);
    return *(const bf16x8*)((const char*)(t + r * RS) + b);
}
__device__ __forceinline__ bf16x8 ld_bp(const short* P, int blk, int lane) {
    return *(const bf16x8*)(P + ((size_t)blk * 64 + lane) * 8);
}

// 9-MFMA split-precision dual step (order identical to r14 -> same numerics)
__device__ __forceinline__ void mf9(bf16x8 f0, bf16x8 f1, bf16x8 f2, bf16x8 fv,
                                    bf16x8 b0, bf16x8 b1, bf16x8 b2,
                                    f32x4& P, f32x4& Q, f32x4& V) {
    P = MFMA(f0, b0, P); Q = MFMA(f1, b1, Q);
    P = MFMA(f1, b0, P); Q = MFMA(f0, b1, Q);
    P = MFMA(f2, b0, P); Q = MFMA(f2, b1, Q);
    P = MFMA(f0, b2, P); Q = MFMA(f1, b2, Q);
    V = MFMA(fv, b0, V);
}

// ---- SHARED layer body (noinline: one I$-resident copy reused by all phases)
struct PQV { f32x4 P, Q, V; };
__device__ __attribute__((noinline))
PQV layerK(const short* a0, const short* a1, const short* a2, const short* av,
           int RS, const short* W0, const short* W1, const short* W2,
           int blk0, int K32, int lane)
{
    f32x4 P = {}, Q = {}, V = {};
    #pragma clang loop unroll(disable)
    for (int ks = 0; ks < K32; ++ks) {
        bf16x8 b0 = ld_bp(W0, blk0 + ks, lane);
        bf16x8 b1 = ld_bp(W1, blk0 + ks, lane);
        bf16x8 b2 = ld_bp(W2, blk0 + ks, lane);
        bf16x8 f0 = ld_af(a0, RS, lane, ks * 32);
        bf16x8 f1 = ld_af(a1, RS, lane, ks * 32);
        bf16x8 f2 = ld_af(a2, RS, lane, ks * 32);
        bf16x8 fv = ld_af(av, RS, lane, ks * 32);
        mf9(f0, f1, f2, fv, b0, b1, b2, P, Q, V);
    }
    PQV r; r.P = P; r.Q = Q; r.V = V;
    return r;
}

__device__ __attribute__((noinline))
void epi_store(short* t0, short* t1, short* t2, short* tv, int RS,
               int lane, int col, f32x4 P, f32x4 Q, f32x4 V, float bb)
{
    #pragma clang loop unroll(disable)
    for (int q = 0; q < 4; ++q) {
        int row = (lane >> 4) * 4 + q;
        float pre = P[q] + Q[q] + bb;
        float h = fmaxf(pre, 0.f);
        short s0, s1, s2;
        split3f(h, s0, s1, s2);
        st_b16(t0, RS, row, col, s0);
        st_b16(t1, RS, row, col, s1);
        st_b16(t2, RS, row, col, s2);
        st_b16(tv, RS, row, col, pre > 0.f ? f2b(V[q]) : (short)0);
    }
}

// =====================================================================
template<int K>
__device__ void pack_w(const float* __restrict__ W, short* __restrict__ dst, int NK,
                       int gid, int nthr)
{
    for (int o = gid; o < NK / 8; o += nthr) {
        int c = o / (K / 8), k0 = (o - c * (K / 8)) * 8;
        int cb = c >> 4, ks = k0 >> 5;
        int L = (((k0 >> 3) & 3) << 4) | (c & 15);
        int idx = ((cb * (K / 32) + ks) * 64 + L) * 8;
        union { short s[8]; bf16x8 v; } p0, p1, p2;
        #pragma unroll
        for (int j = 0; j < 8; ++j)
            split3f(W[(size_t)c * K + k0 + j], p0.s[j], p1.s[j], p2.s[j]);
        *(bf16x8*)(dst + idx) = p0.v;
        *(bf16x8*)(dst + NK + idx) = p1.v;
        *(bf16x8*)(dst + 2 * NK + idx) = p2.v;
    }
}

__global__ void initk(const float* __restrict__ We1, const float* __restrict__ We2,
                      const float* __restrict__ We3, const float* __restrict__ Wd1,
                      const float* __restrict__ Wd2, const float* __restrict__ Wd3,
                      const float* __restrict__ XI, const float* __restrict__ XIm,
                      short* Wp1, short* Wp2, short* Wp3, short* Wp4, short* Wp5, short* Wp6,
                      short* xiP, int2* pk)
{
    int gid = blockIdx.x * blockDim.x + threadIdx.x;
    int nthr = gridDim.x * blockDim.x;

    pack_w<512>(We1, Wp1, WSZ1, gid, nthr);
    pack_w<128>(We2, Wp2, WSZ2, gid, nthr);
    pack_w<64>(We3, Wp3, WSZ3, gid, nthr);
    pack_w<64>(Wd1, Wp4, WSZ4, gid, nthr);
    pack_w<64>(Wd2, Wp5, WSZ5, gid, nthr);
    pack_w<128>(Wd3, Wp6, WSZ6, gid, nthr);

    for (int i = gid; i < 4 * 66 * 64; i += nthr) {
        int cb = i / (66 * 64);
        int r = i - cb * (66 * 64);
        int ks = r >> 6, L = r & 63;
        int col = cb * 16 + (L & 15);
        union { short s[8]; bf16x8 v; } w;
        #pragma unroll
        for (int j = 0; j < 8; ++j) {
            int f = ks * 32 + ((L >> 4) << 3) + j;
            float v = (f < NFUNC) ? XI[(size_t)f * DDIM + col] * XIm[(size_t)f * DDIM + col] : 0.f;
            w.s[j] = f2b(v);
        }
        *(bf16x8*)(xiP + (size_t)i * 8) = w.v;
    }

    for (int f = gid; f < NFPAD; f += nthr) {
        int a, b;
        if (f == 0) { a = 64; b = 64; }
        else if (f <= DDIM) { a = f - 1; b = 64; }
        else if (f < NFUNC) {
            int p = f - 1 - DDIM; int i2 = 0, cum = 0;
            while (cum + (63 - i2) <= p) { cum += 63 - i2; ++i2; }
            a = i2; b = i2 + 1 + (p - cum);
        } else { a = 65; b = 65; }
        pk[f] = make_int2(a, b);
    }
}

// =====================================================================
// 256 blocks x 512 threads (8 waves), ONE 16-row tile per block.
// vs r18: all layer phases route through ONE noinline layerK body and ONE
// noinline epi_store (hot code ~3KB, I$ warm after L1). Numerics identical.
__global__ __launch_bounds__(512, 2)
void fused(const float* __restrict__ x, const float* __restrict__ xdot,
           const float* __restrict__ be1, const float* __restrict__ be2,
           const float* __restrict__ be3, const float* __restrict__ bd1,
           const float* __restrict__ bd2, const float* __restrict__ bd3,
           const short* __restrict__ Wp1, const short* __restrict__ Wp2,
           const short* __restrict__ Wp3, const short* __restrict__ Wp4,
           const short* __restrict__ Wp5, const short* __restrict__ Wp6,
           const short* __restrict__ xiP, const int2* __restrict__ pk,
           float* __restrict__ xh, float* __restrict__ dxh, float* __restrict__ zo,
           float* __restrict__ dz, float* __restrict__ dzs)
{
    __shared__ __align__(16) char ldsbuf[65536];
    short* xs0  = (short*)(ldsbuf + 0);
    short* xs1  = (short*)(ldsbuf + 16384);
    short* xs2  = (short*)(ldsbuf + 32768);
    short* xsv  = (short*)(ldsbuf + 49152);
    short* h1s0 = (short*)(ldsbuf + 0);
    short* h1s1 = (short*)(ldsbuf + 4096);
    short* h1s2 = (short*)(ldsbuf + 8192);
    short* v1   = (short*)(ldsbuf + 12288);
    short* h2s0 = (short*)(ldsbuf + 16384);
    short* h2s1 = (short*)(ldsbuf + 18432);
    short* h2s2 = (short*)(ldsbuf + 20480);
    short* v2   = (short*)(ldsbuf + 22528);
    short* zb0  = (short*)(ldsbuf + 24576);
    short* zb1  = (short*)(ldsbuf + 26624);
    short* zb2  = (short*)(ldsbuf + 28672);
    short* dzsb = (short*)(ldsbuf + 30720);
    float* zf   = (float*)(ldsbuf + 32768);   // [16][68]
    short* th0  = (short*)(ldsbuf + 37888);   // [16][704] swizzled
    short* th1  = (short*)(ldsbuf + 0);       // aliases h1+h2 (dead after L3)
    float* rbuf = (float*)(ldsbuf + 60416);   // [4 cb][64 lane][4] f32
    short* g1s0 = (short*)(ldsbuf + 0);
    short* g1s1 = (short*)(ldsbuf + 2048);
    short* g1s2 = (short*)(ldsbuf + 4096);
    short* u1   = (short*)(ldsbuf + 6144);
    short* g2s0 = (short*)(ldsbuf + 8192);
    short* g2s1 = (short*)(ldsbuf + 12288);
    short* g2s2 = (short*)(ldsbuf + 16384);
    short* u2   = (short*)(ldsbuf + 20480);

    const int tid = threadIdx.x, lane = tid & 63, wave = tid >> 6;
    const int wq = wave & 3;
    const int row0 = blockIdx.x * 16;
    const int c16 = lane & 15;
    const int tr = tid & 15, bg = tid >> 4;     // builder: 32 groups x 16 rows
    const int tf = bg * 22;                     // 22 funcs per builder group
    const int scb = wave & 3, skh = wave >> 2;  // SINDy: col-block, K-half

    // ---- bias preload ----
    float bb1 = be1[wave * 16 + c16];
    float bb2 = be2[wq * 16 + c16];
    float bb3 = be3[wq * 16 + c16];
    float bD1 = bd1[wq * 16 + c16];
    float bD2 = bd2[wave * 16 + c16];
    float bD3[4];
    #pragma unroll
    for (int i = 0; i < 4; ++i) bD3[i] = bd3[wave * 64 + i * 16 + c16];

    // ================= encoder L1 (K=512, N=128): stage full K, one layerK ====
    {
        const int srow = tid >> 5, sc0 = (tid & 31) * 8;   // staging: row, k-octet
        const float* xr  = x    + (size_t)(row0 + srow) * IN_DIM + sc0;
        const float* xdr = xdot + (size_t)(row0 + srow) * IN_DIM + sc0;
        f32x4 va0 = *(const f32x4*)(xr);        f32x4 vb0 = *(const f32x4*)(xr + 4);
        f32x4 da0 = *(const f32x4*)(xdr);       f32x4 db0 = *(const f32x4*)(xdr + 4);
        f32x4 va1 = *(const f32x4*)(xr + 256);  f32x4 vb1 = *(const f32x4*)(xr + 260);
        f32x4 da1 = *(const f32x4*)(xdr + 256); f32x4 db1 = *(const f32x4*)(xdr + 260);
        {
            union { short s[8]; bf16x8 v; } a0, a1, a2, dv;
            #pragma unroll
            for (int j = 0; j < 4; ++j) {
                split3f(va0[j], a0.s[j], a1.s[j], a2.s[j]);
                split3f(vb0[j], a0.s[j + 4], a1.s[j + 4], a2.s[j + 4]);
                dv.s[j] = f2b(da0[j]); dv.s[j + 4] = f2b(db0[j]);
            }
            st_b128(xs0, 512, srow, sc0, a0.v);
            st_b128(xs1, 512, srow, sc0, a1.v);
            st_b128(xs2, 512, srow, sc0, a2.v);
            st_b128(xsv, 512, srow, sc0, dv.v);
        }
        {
            union { short s[8]; bf16x8 v; } a0, a1, a2, dv;
            #pragma unroll
            for (int j = 0; j < 4; ++j) {
                split3f(va1[j], a0.s[j], a1.s[j], a2.s[j]);
                split3f(vb1[j], a0.s[j + 4], a1.s[j + 4], a2.s[j + 4]);
                dv.s[j] = f2b(da1[j]); dv.s[j + 4] = f2b(db1[j]);
            }
            st_b128(xs0, 512, srow, sc0 + 256, a0.v);
            st_b128(xs1, 512, srow, sc0 + 256, a1.v);
            st_b128(xs2, 512, srow, sc0 + 256, a2.v);
            st_b128(xsv, 512, srow, sc0 + 256, dv.v);
        }
        barrier_lds();   // xs (full K) ready
        PQV r = layerK(xs0, xs1, xs2, xsv, 512,
                       Wp1, Wp1 + WSZ1, Wp1 + 2 * WSZ1, wave * 16, 16, lane);
        barrier_lds();   // all waves done reading xs -> h1 region reusable
        epi_store(h1s0, h1s1, h1s2, v1, 128, lane, wave * 16 + c16, r.P, r.Q, r.V, bb1);
    }
    barrier_lds();   // h1 ready

    // ================= encoder L2 (K=128, N=64): waves 0-3 ====
    if (wave < 4) {
        PQV r = layerK(h1s0, h1s1, h1s2, v1, 128,
                       Wp2, Wp2 + WSZ2, Wp2 + 2 * WSZ2, wq * 4, 4, lane);
        epi_store(h2s0, h2s1, h2s2, v2, 64, lane, wq * 16 + c16, r.P, r.Q, r.V, bb2);
    }
    barrier_lds();

    // ================= encoder L3 (K=64) -> z: waves 0-3; ALL preload X ====
    bf16x8 X[11];
    if (wave < 4) {
        PQV r = layerK(h2s0, h2s1, h2s2, v2, 64,
                       Wp3, Wp3 + WSZ3, Wp3 + 2 * WSZ3, wq * 2, 2, lane);
        int col = wq * 16 + c16;
        #pragma unroll
        for (int q = 0; q < 4; ++q) {
            int row = (lane >> 4) * 4 + q;
            float pre = r.P[q] + r.Q[q] + bb3;
            float hz = fmaxf(pre, 0.f);
            float vz = pre > 0.f ? r.V[q] : 0.f;
            zf[row * 68 + col] = hz;
            short s0, s1, s2;
            split3f(hz, s0, s1, s2);
            st_b16(zb0, 64, row, col, s0);
            st_b16(zb1, 64, row, col, s1);
            st_b16(zb2, 64, row, col, s2);
            zo[(size_t)(row0 + row) * DDIM + col] = hz;
            dz[(size_t)(row0 + row) * DDIM + col] = vz;
        }
        if (tid < 32) { int r2 = tid & 15; zf[r2 * 68 + 64 + (tid >> 4)] = (tid >> 4) ? 0.f : 1.f; }
    }
    #pragma unroll
    for (int kk = 0; kk < 11; ++kk)
        X[kk] = ld_bp(xiP, scb * 66 + skh * 11 + kk, lane);
    barrier_lds();   // zf/zb ready; h1/h2/xs dead -> th0/th1 may overwrite

    // ================= SINDy: dbuf theta; SMF K-split over 8 waves ====
    f32x4 sa = {};
    auto build = [&](int ch, short* t) {
        #pragma clang loop unroll(disable)
        for (int j = 0; j < 11; ++j) {
            int f0 = ch * CHUNK + tf + 2 * j;
            int2 p0 = pk[f0], p1 = pk[f0 + 1];
            float t0 = zf[tr * 68 + p0.x] * zf[tr * 68 + p0.y];
            float t1 = zf[tr * 68 + p1.x] * zf[tr * 68 + p1.y];
            unsigned u = (unsigned)(unsigned short)f2b(t0)
                       | ((unsigned)(unsigned short)f2b(t1) << 16);
            st_b32s(t, 704, tr, tf + 2 * j, u);
        }
    };
#define SMF(t) { _Pragma("unroll") for (int kk = 0; kk < 11; ++kk) { \
        bf16x8 a = ld_af(t, 704, lane, (skh * 11 + kk) * 32); \
        sa = MFMA(a, X[kk], sa); } }
#define ISX(ch) { _Pragma("unroll") for (int kk = 0; kk < 11; ++kk) \
        X[kk] = ld_bp(xiP, scb * 66 + (ch) * KS_PER_CHUNK + skh * 11 + kk, lane); }

    build(0, th0);
    barrier_lds();
    SMF(th0) ISX(1) build(1, th1);
    barrier_lds();
    SMF(th1) ISX(2) build(2, th0);
    barrier_lds();
    SMF(th0)
    if (wave >= 4) *(f32x4*)&rbuf[(scb * 64 + lane) * 4] = sa;   // park upper-K partials
    barrier_lds();
    if (wave < 4) {
        f32x4 sacc = sa + *(const f32x4*)&rbuf[(scb * 64 + lane) * 4];
        int col = wq * 16 + c16;
        #pragma unroll
        for (int q = 0; q < 4; ++q) {
            int row = (lane >> 4) * 4 + q;
            float v = sacc[q];
            dzs[(size_t)(row0 + row) * DDIM + col] = v;
            st_b16(dzsb, 64, row, col, f2b(v));
        }
    }
#undef SMF
#undef ISX
    barrier_lds();   // dzsb ready; th dead -> g1 may overwrite

    // ================= decoder L1 (K=64): waves 0-3 ====
    if (wave < 4) {
        PQV r = layerK(zb0, zb1, zb2, dzsb, 64,
                       Wp4, Wp4 + WSZ4, Wp4 + 2 * WSZ4, wq * 2, 2, lane);
        epi_store(g1s0, g1s1, g1s2, u1, 64, lane, wq * 16 + c16, r.P, r.Q, r.V, bD1);
    }
    barrier_lds();

    // ================= decoder L2 (K=64, N=128): all 8 waves, 1 frag each ====
    {
        PQV r = layerK(g1s0, g1s1, g1s2, u1, 64,
                       Wp5, Wp5 + WSZ5, Wp5 + 2 * WSZ5, wave * 2, 2, lane);
        epi_store(g2s0, g2s1, g2s2, u2, 128, lane, wave * 16 + c16, r.P, r.Q, r.V, bD2);
    }
    barrier_lds();

    // ================= decoder L3 (K=128, N=512): all 8 waves, 4 layerK calls ====
    {
        #pragma clang loop unroll(disable)
        for (int cf = 0; cf < 4; ++cf) {
            PQV r = layerK(g2s0, g2s1, g2s2, u2, 128,
                           Wp6, Wp6 + WSZ6, Wp6 + 2 * WSZ6, (wave * 4 + cf) * 4, 4, lane);
            int col = wave * 64 + cf * 16 + c16;
            float bb = bD3[cf];
            #pragma unroll
            for (int q = 0; q < 4; ++q) {
                int row = (lane >> 4) * 4 + q;
                float pre = r.P[q] + r.Q[q] + bb;
                xh[(size_t)(row0 + row) * IN_DIM + col] = fmaxf(pre, 0.f);
                dxh[(size_t)(row0 + row) * IN_DIM + col] = pre > 0.f ? r.V[q] : 0.f;
            }
        }
    }
}

// =====================================================================
extern "C" void kernel_launch(void* const* d_in, const int* in_sizes, int n_in,
                              void* d_out, int out_size, void* d_ws, size_t ws_size,
                              hipStream_t stream)
{
    const float* x    = (const float*)d_in[0];
    const float* xdot = (const float*)d_in[1];
    const float* We1  = (const float*)d_in[2];
    const float* be1  = (const float*)d_in[3];
    const float* We2  = (const float*)d_in[4];
    const float* be2  = (const float*)d_in[5];
    const float* We3  = (const float*)d_in[6];
    const float* be3  = (const float*)d_in[7];
    const float* Wd1  = (const float*)d_in[8];
    const float* bd1  = (const float*)d_in[9];
    const float* Wd2  = (const float*)d_in[10];
    const float* bd2  = (const float*)d_in[11];
    const float* Wd3  = (const float*)d_in[12];
    const float* bd3  = (const float*)d_in[13];
    const float* XI   = (const float*)d_in[14];
    const float* XIm  = (const float*)d_in[15];

    float* out = (float*)d_out;
    float* xh  = out;
    float* dxh = out + (size_t)BATCH * IN_DIM;
    float* zo  = dxh + (size_t)BATCH * IN_DIM;
    float* dz  = zo + (size_t)BATCH * DDIM;
    float* dzs = dz + (size_t)BATCH * DDIM;

    int2*  pk  = (int2*)d_ws;
    short* Wp1 = (short*)(pk + NFPAD);
    short* Wp2 = Wp1 + 3 * WSZ1;
    short* Wp3 = Wp2 + 3 * WSZ2;
    short* Wp4 = Wp3 + 3 * WSZ3;
    short* Wp5 = Wp4 + 3 * WSZ4;
    short* Wp6 = Wp5 + 3 * WSZ5;
    short* xiP = Wp6 + 3 * WSZ6;

    initk<<<256, 256, 0, stream>>>(We1, We2, We3, Wd1, Wd2, Wd3, XI, XIm,
                                   Wp1, Wp2, Wp3, Wp4, Wp5, Wp6, xiP, pk);
    fused<<<BATCH / 16, 512, 0, stream>>>(x, xdot, be1, be2, be3, bd1, bd2, bd3,
                                          Wp1, Wp2, Wp3, Wp4, Wp5, Wp6, xiP, pk,
                                          xh, dxh, zo, dz, dzs);
}

// Round 20
// 42.436 us; speedup vs baseline: 1.3987x; 1.3987x over previous
//
#include <hip/hip_runtime.h>

#define BATCH 4096
#define IN_DIM 512
#define H1DIM 128
#define H2DIM 64
#define DDIM 64
#define NFUNC 2081
#define NFPAD 2112
#define CHUNK 704           // 2112 = 3 * 704
#define KS_PER_CHUNK 22     // 704/32

typedef short bf16x8 __attribute__((ext_vector_type(8)));
typedef float f32x4 __attribute__((ext_vector_type(4)));
#define MFMA(a,b,c) __builtin_amdgcn_mfma_f32_16x16x32_bf16(a,b,c,0,0,0)

#define WSZ1 (H1DIM*IN_DIM)
#define WSZ2 (H2DIM*H1DIM)
#define WSZ3 (DDIM*H2DIM)
#define WSZ4 (H2DIM*DDIM)
#define WSZ5 (H1DIM*H2DIM)
#define WSZ6 (IN_DIM*H1DIM)

__device__ __forceinline__ short f2b(float f) {
    union { float f; unsigned u; } x; x.f = f;
    unsigned r = x.u + 0x7fffu + ((x.u >> 16) & 1u);
    return (short)(r >> 16);
}
__device__ __forceinline__ float b2f(short s) {
    union { unsigned u; float f; } x; x.u = ((unsigned)(unsigned short)s) << 16;
    return x.f;
}
__device__ __forceinline__ void split3f(float v, short& s0, short& s1, short& s2) {
    s0 = f2b(v); float r = v - b2f(s0);
    s1 = f2b(r); float r2 = r - b2f(s1);
    s2 = f2b(r2);
}

// ---- swizzled LDS tile helpers (row stride RS shorts, byte ^= (r&7)<<4) ----
__device__ __forceinline__ void st_b16(short* t, int RS, int r, int c, short v) {
    int b = (c * 2) ^ ((r & 7) << 4);
    *(short*)((char*)(t + r * RS) + b) = v;
}
__device__ __forceinline__ void st_b32s(short* t, int RS, int r, int c, unsigned v) {
    int b = (c * 2) ^ ((r & 7) << 4);   // c even -> 4B aligned
    *(unsigned*)((char*)(t + r * RS) + b) = v;
}
// 16B store of 8 consecutive k (c0 multiple of 8 -> one swizzle block)
__device__ __forceinline__ void st_b128(short* t, int RS, int r, int c0, bf16x8 v) {
    int b = (c0 * 2) ^ ((r & 7) << 4);
    *(bf16x8*)((char*)(t + r * RS) + b) = v;
}
__device__ __forceinline__ bf16x8 ld_af(const short* t, int RS, int lane, int kbase) {
    int r = lane & 15;
    int b = ((kbase + (lane >> 4) * 8) * 2) ^ ((r & 7) << 4);
    return *(const bf16x8*)((const char*)(t + r * RS) + b);
}
__device__ __forceinline__ bf16x8 ld_bp(const short* P, int blk, int lane) {
    return *(const bf16x8*)(P + ((size_t)blk * 64 + lane) * 8);
}

// 9-MFMA split-precision dual step
__device__ __forceinline__ void mf9(bf16x8 f0, bf16x8 f1, bf16x8 f2, bf16x8 fv,
                                    bf16x8 b0, bf16x8 b1, bf16x8 b2,
                                    f32x4& P, f32x4& Q, f32x4& V) {
    P = MFMA(f0, b0, P); Q = MFMA(f1, b1, Q);
    P = MFMA(f1, b0, P); Q = MFMA(f0, b1, Q);
    P = MFMA(f2, b0, P); Q = MFMA(f2, b1, Q);
    P = MFMA(f0, b2, P); Q = MFMA(f1, b2, Q);
    V = MFMA(fv, b0, V);
}

__device__ __forceinline__ void epi_store(short* t0, short* t1, short* t2, short* tv, int RS,
                                          int lane, int col, const f32x4& P, const f32x4& Q,
                                          const f32x4& V, float bb)
{
    #pragma unroll
    for (int q = 0; q < 4; ++q) {
        int row = (lane >> 4) * 4 + q;
        float pre = P[q] + Q[q] + bb;
        float h = fmaxf(pre, 0.f);
        short s0, s1, s2;
        split3f(h, s0, s1, s2);
        st_b16(t0, RS, row, col, s0);
        st_b16(t1, RS, row, col, s1);
        st_b16(t2, RS, row, col, s2);
        st_b16(tv, RS, row, col, pre > 0.f ? f2b(V[q]) : (short)0);
    }
}

// =====================================================================
template<int K>
__device__ void pack_w(const float* __restrict__ W, short* __restrict__ dst, int NK,
                       int gid, int nthr)
{
    for (int o = gid; o < NK / 8; o += nthr) {
        int c = o / (K / 8), k0 = (o - c * (K / 8)) * 8;
        int cb = c >> 4, ks = k0 >> 5;
        int L = (((k0 >> 3) & 3) << 4) | (c & 15);
        int idx = ((cb * (K / 32) + ks) * 64 + L) * 8;
        union { short s[8]; bf16x8 v; } p0, p1, p2;
        #pragma unroll
        for (int j = 0; j < 8; ++j)
            split3f(W[(size_t)c * K + k0 + j], p0.s[j], p1.s[j], p2.s[j]);
        *(bf16x8*)(dst + idx) = p0.v;
        *(bf16x8*)(dst + NK + idx) = p1.v;
        *(bf16x8*)(dst + 2 * NK + idx) = p2.v;
    }
}

__global__ void initk(const float* __restrict__ We1, const float* __restrict__ We2,
                      const float* __restrict__ We3, const float* __restrict__ Wd1,
                      const float* __restrict__ Wd2, const float* __restrict__ Wd3,
                      const float* __restrict__ XI, const float* __restrict__ XIm,
                      short* Wp1, short* Wp2, short* Wp3, short* Wp4, short* Wp5, short* Wp6,
                      short* xiP, int2* pk)
{
    int gid = blockIdx.x * blockDim.x + threadIdx.x;
    int nthr = gridDim.x * blockDim.x;

    pack_w<512>(We1, Wp1, WSZ1, gid, nthr);
    pack_w<128>(We2, Wp2, WSZ2, gid, nthr);
    pack_w<64>(We3, Wp3, WSZ3, gid, nthr);
    pack_w<64>(Wd1, Wp4, WSZ4, gid, nthr);
    pack_w<64>(Wd2, Wp5, WSZ5, gid, nthr);
    pack_w<128>(Wd3, Wp6, WSZ6, gid, nthr);

    for (int i = gid; i < 4 * 66 * 64; i += nthr) {
        int cb = i / (66 * 64);
        int r = i - cb * (66 * 64);
        int ks = r >> 6, L = r & 63;
        int col = cb * 16 + (L & 15);
        union { short s[8]; bf16x8 v; } w;
        #pragma unroll
        for (int j = 0; j < 8; ++j) {
            int f = ks * 32 + ((L >> 4) << 3) + j;
            float v = (f < NFUNC) ? XI[(size_t)f * DDIM + col] * XIm[(size_t)f * DDIM + col] : 0.f;
            w.s[j] = f2b(v);
        }
        *(bf16x8*)(xiP + (size_t)i * 8) = w.v;
    }

    for (int f = gid; f < NFPAD; f += nthr) {
        int a, b;
        if (f == 0) { a = 64; b = 64; }
        else if (f <= DDIM) { a = f - 1; b = 64; }
        else if (f < NFUNC) {
            int p = f - 1 - DDIM; int i2 = 0, cum = 0;
            while (cum + (63 - i2) <= p) { cum += 63 - i2; ++i2; }
            a = i2; b = i2 + 1 + (p - cum);
        } else { a = 65; b = 65; }
        pk[f] = make_int2(a, b);
    }
}

// =====================================================================
// 256 blocks x 512 threads (8 waves), ONE 16-row tile per block.
// Champion configuration (r17): single-pass full-K L1 staging, SINDy theta
// double-buffer + 8-wave SMF K-split, cross-phase B prefetches, 12 barriers.
__global__ __launch_bounds__(512, 2)
void fused(const float* __restrict__ x, const float* __restrict__ xdot,
           const float* __restrict__ be1, const float* __restrict__ be2,
           const float* __restrict__ be3, const float* __restrict__ bd1,
           const float* __restrict__ bd2, const float* __restrict__ bd3,
           const short* __restrict__ Wp1, const short* __restrict__ Wp2,
           const short* __restrict__ Wp3, const short* __restrict__ Wp4,
           const short* __restrict__ Wp5, const short* __restrict__ Wp6,
           const short* __restrict__ xiP, const int2* __restrict__ pk,
           float* __restrict__ xh, float* __restrict__ dxh, float* __restrict__ zo,
           float* __restrict__ dz, float* __restrict__ dzs)
{
    __shared__ __align__(16) char ldsbuf[65536];
    short* xs0  = (short*)(ldsbuf + 0);
    short* xs1  = (short*)(ldsbuf + 16384);
    short* xs2  = (short*)(ldsbuf + 32768);
    short* xsv  = (short*)(ldsbuf + 49152);
    short* h1s0 = (short*)(ldsbuf + 0);
    short* h1s1 = (short*)(ldsbuf + 4096);
    short* h1s2 = (short*)(ldsbuf + 8192);
    short* v1   = (short*)(ldsbuf + 12288);
    short* h2s0 = (short*)(ldsbuf + 16384);
    short* h2s1 = (short*)(ldsbuf + 18432);
    short* h2s2 = (short*)(ldsbuf + 20480);
    short* v2   = (short*)(ldsbuf + 22528);
    short* zb0  = (short*)(ldsbuf + 24576);
    short* zb1  = (short*)(ldsbuf + 26624);
    short* zb2  = (short*)(ldsbuf + 28672);
    short* dzsb = (short*)(ldsbuf + 30720);
    float* zf   = (float*)(ldsbuf + 32768);   // [16][68]
    short* th0  = (short*)(ldsbuf + 37888);   // [16][704] swizzled
    short* th1  = (short*)(ldsbuf + 0);       // aliases h1+h2 (dead after L3)
    float* rbuf = (float*)(ldsbuf + 60416);   // [4 cb][64 lane][4] f32
    short* g1s0 = (short*)(ldsbuf + 0);
    short* g1s1 = (short*)(ldsbuf + 2048);
    short* g1s2 = (short*)(ldsbuf + 4096);
    short* u1   = (short*)(ldsbuf + 6144);
    short* g2s0 = (short*)(ldsbuf + 8192);
    short* g2s1 = (short*)(ldsbuf + 12288);
    short* g2s2 = (short*)(ldsbuf + 16384);
    short* u2   = (short*)(ldsbuf + 20480);

    const int tid = threadIdx.x, lane = tid & 63, wave = tid >> 6;
    const int wq = wave & 3;
    const int row0 = blockIdx.x * 16;
    const int c16 = lane & 15;
    const int tr = tid & 15, bg = tid >> 4;     // builder: 32 groups x 16 rows
    const int tf = bg * 22;                     // 22 funcs per builder group
    const int scb = wave & 3, skh = wave >> 2;  // SINDy: col-block, K-half

    // ---- bias preload ----
    float bb1 = be1[wave * 16 + c16];
    float bb2 = be2[wq * 16 + c16];
    float bb3 = be3[wq * 16 + c16];
    float bD1 = bd1[wq * 16 + c16];
    float bD2 = bd2[wave * 16 + c16];
    float bD3[4];
    #pragma unroll
    for (int i = 0; i < 4; ++i) bD3[i] = bd3[wave * 64 + i * 16 + c16];

    // ================= encoder L1 (K=512, N=128): single-pass full-K ====
    f32x4 P1 = {}, Q1 = {}, V1 = {};
    {
        const int srow = tid >> 5, sc0 = (tid & 31) * 8;   // staging: row, k-octet
        const float* xr  = x    + (size_t)(row0 + srow) * IN_DIM + sc0;
        const float* xdr = xdot + (size_t)(row0 + srow) * IN_DIM + sc0;
        f32x4 va0 = *(const f32x4*)(xr);        f32x4 vb0 = *(const f32x4*)(xr + 4);
        f32x4 da0 = *(const f32x4*)(xdr);       f32x4 db0 = *(const f32x4*)(xdr + 4);
        f32x4 va1 = *(const f32x4*)(xr + 256);  f32x4 vb1 = *(const f32x4*)(xr + 260);
        f32x4 da1 = *(const f32x4*)(xdr + 256); f32x4 db1 = *(const f32x4*)(xdr + 260);
        {
            union { short s[8]; bf16x8 v; } a0, a1, a2, dv;
            #pragma unroll
            for (int j = 0; j < 4; ++j) {
                split3f(va0[j], a0.s[j], a1.s[j], a2.s[j]);
                split3f(vb0[j], a0.s[j + 4], a1.s[j + 4], a2.s[j + 4]);
                dv.s[j] = f2b(da0[j]); dv.s[j + 4] = f2b(db0[j]);
            }
            st_b128(xs0, 512, srow, sc0, a0.v);
            st_b128(xs1, 512, srow, sc0, a1.v);
            st_b128(xs2, 512, srow, sc0, a2.v);
            st_b128(xsv, 512, srow, sc0, dv.v);
        }
        {
            union { short s[8]; bf16x8 v; } a0, a1, a2, dv;
            #pragma unroll
            for (int j = 0; j < 4; ++j) {
                split3f(va1[j], a0.s[j], a1.s[j], a2.s[j]);
                split3f(vb1[j], a0.s[j + 4], a1.s[j + 4], a2.s[j + 4]);
                dv.s[j] = f2b(da1[j]); dv.s[j + 4] = f2b(db1[j]);
            }
            st_b128(xs0, 512, srow, sc0 + 256, a0.v);
            st_b128(xs1, 512, srow, sc0 + 256, a1.v);
            st_b128(xs2, 512, srow, sc0 + 256, a2.v);
            st_b128(xsv, 512, srow, sc0 + 256, dv.v);
        }
        __syncthreads();   // xs (full K) ready
        bf16x8 B0[2], B1[2], B2[2];
        {
            int blk = wave * 16;
            B0[0] = ld_bp(Wp1, blk, lane); B1[0] = ld_bp(Wp1 + WSZ1, blk, lane);
            B2[0] = ld_bp(Wp1 + 2 * WSZ1, blk, lane);
        }
        #pragma unroll
        for (int ks = 0; ks < 16; ++ks) {
            if (ks < 15) {
                int blk = wave * 16 + ks + 1;
                B0[(ks + 1) & 1] = ld_bp(Wp1, blk, lane);
                B1[(ks + 1) & 1] = ld_bp(Wp1 + WSZ1, blk, lane);
                B2[(ks + 1) & 1] = ld_bp(Wp1 + 2 * WSZ1, blk, lane);
            }
            bf16x8 f0 = ld_af(xs0, 512, lane, ks * 32);
            bf16x8 f1 = ld_af(xs1, 512, lane, ks * 32);
            bf16x8 f2 = ld_af(xs2, 512, lane, ks * 32);
            bf16x8 fv = ld_af(xsv, 512, lane, ks * 32);
            mf9(f0, f1, f2, fv, B0[ks & 1], B1[ks & 1], B2[ks & 1], P1, Q1, V1);
        }
        __syncthreads();   // all waves done reading xs -> h1 region reusable
        epi_store(h1s0, h1s1, h1s2, v1, 128, lane, wave * 16 + c16, P1, Q1, V1, bb1);
    }
    bf16x8 L2B[4][3];
    if (wave < 4) {
        #pragma unroll
        for (int ks = 0; ks < 4; ++ks) {
            int blk = wq * 4 + ks;
            L2B[ks][0] = ld_bp(Wp2, blk, lane);
            L2B[ks][1] = ld_bp(Wp2 + WSZ2, blk, lane);
            L2B[ks][2] = ld_bp(Wp2 + 2 * WSZ2, blk, lane);
        }
    }
    __syncthreads();   // h1 ready

    // ================= encoder L2 (K=128, N=64): waves 0-3 ====
    bf16x8 L3B[2][3];
    if (wave < 4) {
        bf16x8 Aa[4][4];
        #pragma unroll
        for (int ks = 0; ks < 4; ++ks) {
            Aa[ks][0] = ld_af(h1s0, 128, lane, ks * 32);
            Aa[ks][1] = ld_af(h1s1, 128, lane, ks * 32);
            Aa[ks][2] = ld_af(h1s2, 128, lane, ks * 32);
            Aa[ks][3] = ld_af(v1, 128, lane, ks * 32);
        }
        #pragma unroll
        for (int ks = 0; ks < 2; ++ks) {
            int blk = wq * 2 + ks;
            L3B[ks][0] = ld_bp(Wp3, blk, lane);
            L3B[ks][1] = ld_bp(Wp3 + WSZ3, blk, lane);
            L3B[ks][2] = ld_bp(Wp3 + 2 * WSZ3, blk, lane);
        }
        f32x4 P = {}, Q = {}, V = {};
        #pragma unroll
        for (int ks = 0; ks < 4; ++ks)
            mf9(Aa[ks][0], Aa[ks][1], Aa[ks][2], Aa[ks][3], L2B[ks][0], L2B[ks][1], L2B[ks][2], P, Q, V);
        epi_store(h2s0, h2s1, h2s2, v2, 64, lane, wq * 16 + c16, P, Q, V, bb2);
    }
    __syncthreads();

    // ================= encoder L3 (K=64) -> z: waves 0-3; ALL preload X ====
    bf16x8 X[11];
    if (wave < 4) {
        bf16x8 Aa[2][4];
        #pragma unroll
        for (int ks = 0; ks < 2; ++ks) {
            Aa[ks][0] = ld_af(h2s0, 64, lane, ks * 32);
            Aa[ks][1] = ld_af(h2s1, 64, lane, ks * 32);
            Aa[ks][2] = ld_af(h2s2, 64, lane, ks * 32);
            Aa[ks][3] = ld_af(v2, 64, lane, ks * 32);
        }
        f32x4 P = {}, Q = {}, V = {};
        #pragma unroll
        for (int ks = 0; ks < 2; ++ks)
            mf9(Aa[ks][0], Aa[ks][1], Aa[ks][2], Aa[ks][3], L3B[ks][0], L3B[ks][1], L3B[ks][2], P, Q, V);
        int col = wq * 16 + c16;
        #pragma unroll
        for (int q = 0; q < 4; ++q) {
            int row = (lane >> 4) * 4 + q;
            float pre = P[q] + Q[q] + bb3;
            float hz = fmaxf(pre, 0.f);
            float vz = pre > 0.f ? V[q] : 0.f;
            zf[row * 68 + col] = hz;
            short s0, s1, s2;
            split3f(hz, s0, s1, s2);
            st_b16(zb0, 64, row, col, s0);
            st_b16(zb1, 64, row, col, s1);
            st_b16(zb2, 64, row, col, s2);
            zo[(size_t)(row0 + row) * DDIM + col] = hz;
            dz[(size_t)(row0 + row) * DDIM + col] = vz;
        }
        if (tid < 32) { int r = tid & 15; zf[r * 68 + 64 + (tid >> 4)] = (tid >> 4) ? 0.f : 1.f; }
    }
    #pragma unroll
    for (int kk = 0; kk < 11; ++kk)
        X[kk] = ld_bp(xiP, scb * 66 + skh * 11 + kk, lane);
    __syncthreads();   // zf/zb ready; h1/h2/xs dead -> th0/th1 may overwrite

    // ================= SINDy: dbuf theta; SMF K-split over 8 waves ====
    f32x4 sa = {};
    auto build = [&](int ch, short* t) {
        #pragma clang loop unroll(disable)
        for (int j = 0; j < 11; ++j) {
            int f0 = ch * CHUNK + tf + 2 * j;
            int2 p0 = pk[f0], p1 = pk[f0 + 1];
            float t0 = zf[tr * 68 + p0.x] * zf[tr * 68 + p0.y];
            float t1 = zf[tr * 68 + p1.x] * zf[tr * 68 + p1.y];
            unsigned u = (unsigned)(unsigned short)f2b(t0)
                       | ((unsigned)(unsigned short)f2b(t1) << 16);
            st_b32s(t, 704, tr, tf + 2 * j, u);
        }
    };
#define SMF(t) { _Pragma("unroll") for (int kk = 0; kk < 11; ++kk) { \
        bf16x8 a = ld_af(t, 704, lane, (skh * 11 + kk) * 32); \
        sa = MFMA(a, X[kk], sa); } }
#define ISX(ch) { _Pragma("unroll") for (int kk = 0; kk < 11; ++kk) \
        X[kk] = ld_bp(xiP, scb * 66 + (ch) * KS_PER_CHUNK + skh * 11 + kk, lane); }

    build(0, th0);
    __syncthreads();
    SMF(th0) ISX(1) build(1, th1);
    __syncthreads();
    SMF(th1) ISX(2) build(2, th0);
    __syncthreads();
    SMF(th0)
    if (wave >= 4) *(f32x4*)&rbuf[(scb * 64 + lane) * 4] = sa;   // park upper-K partials
    __syncthreads();
    bf16x8 D1B[2][3];
    if (wave < 4) {
        f32x4 sacc = sa + *(const f32x4*)&rbuf[(scb * 64 + lane) * 4];
        #pragma unroll
        for (int ks = 0; ks < 2; ++ks) {
            int blk = wq * 2 + ks;
            D1B[ks][0] = ld_bp(Wp4, blk, lane);
            D1B[ks][1] = ld_bp(Wp4 + WSZ4, blk, lane);
            D1B[ks][2] = ld_bp(Wp4 + 2 * WSZ4, blk, lane);
        }
        int col = wq * 16 + c16;
        #pragma unroll
        for (int q = 0; q < 4; ++q) {
            int row = (lane >> 4) * 4 + q;
            float v = sacc[q];
            dzs[(size_t)(row0 + row) * DDIM + col] = v;
            st_b16(dzsb, 64, row, col, f2b(v));
        }
    }
#undef SMF
#undef ISX
    __syncthreads();   // dzsb ready; th dead -> g1 may overwrite

    // ================= decoder L1 (K=64): waves 0-3; all waves prefetch D2B ====
    bf16x8 D2B[2][3];
    if (wave < 4) {
        bf16x8 Aa[2][4];
        #pragma unroll
        for (int ks = 0; ks < 2; ++ks) {
            Aa[ks][0] = ld_af(zb0, 64, lane, ks * 32);
            Aa[ks][1] = ld_af(zb1, 64, lane, ks * 32);
            Aa[ks][2] = ld_af(zb2, 64, lane, ks * 32);
            Aa[ks][3] = ld_af(dzsb, 64, lane, ks * 32);
        }
        f32x4 P = {}, Q = {}, V = {};
        #pragma unroll
        for (int ks = 0; ks < 2; ++ks)
            mf9(Aa[ks][0], Aa[ks][1], Aa[ks][2], Aa[ks][3], D1B[ks][0], D1B[ks][1], D1B[ks][2], P, Q, V);
        epi_store(g1s0, g1s1, g1s2, u1, 64, lane, wq * 16 + c16, P, Q, V, bD1);
    }
    #pragma unroll
    for (int ks = 0; ks < 2; ++ks) {       // ALL waves: own dec2 B (N=128, cb=wave)
        int blk = wave * 2 + ks;
        D2B[ks][0] = ld_bp(Wp5, blk, lane);
        D2B[ks][1] = ld_bp(Wp5 + WSZ5, blk, lane);
        D2B[ks][2] = ld_bp(Wp5 + 2 * WSZ5, blk, lane);
    }
    __syncthreads();

    // ================= decoder L2 (K=64, N=128): all 8 waves, 1 frag each ====
    {
        bf16x8 Aa[2][4];
        #pragma unroll
        for (int ks = 0; ks < 2; ++ks) {
            Aa[ks][0] = ld_af(g1s0, 64, lane, ks * 32);
            Aa[ks][1] = ld_af(g1s1, 64, lane, ks * 32);
            Aa[ks][2] = ld_af(g1s2, 64, lane, ks * 32);
            Aa[ks][3] = ld_af(u1, 64, lane, ks * 32);
        }
        f32x4 P = {}, Q = {}, V = {};
        #pragma unroll
        for (int ks = 0; ks < 2; ++ks)
            mf9(Aa[ks][0], Aa[ks][1], Aa[ks][2], Aa[ks][3], D2B[ks][0], D2B[ks][1], D2B[ks][2], P, Q, V);
        epi_store(g2s0, g2s1, g2s2, u2, 128, lane, wave * 16 + c16, P, Q, V, bD2);
    }
    __syncthreads();

    // ================= decoder L3 (K=128, N=512): all 8 waves, 64 cols each ====
    {
        f32x4 P[4] = {}, Q[4] = {}, V[4] = {};
        bf16x8 Bp[4][3];
        bf16x8 Ax0[2], Ax1[2], Ax2[2], Axv[2];
#define D3_LA(ks, b) { Ax0[b] = ld_af(g2s0, 128, lane, (ks) * 32); Ax1[b] = ld_af(g2s1, 128, lane, (ks) * 32); \
                       Ax2[b] = ld_af(g2s2, 128, lane, (ks) * 32); Axv[b] = ld_af(u2, 128, lane, (ks) * 32); }
#define D3_LB(s, sl) { int blk = (wave * 4 + ((s) & 3)) * 4 + ((s) >> 2); \
        Bp[sl][0] = ld_bp(Wp6, blk, lane); Bp[sl][1] = ld_bp(Wp6 + WSZ6, blk, lane); \
        Bp[sl][2] = ld_bp(Wp6 + 2 * WSZ6, blk, lane); }
        D3_LA(0, 0)
        D3_LB(0, 0) D3_LB(1, 1) D3_LB(2, 2) D3_LB(3, 3)
        #pragma unroll
        for (int ks = 0; ks < 4; ++ks) {
            if (ks < 3) D3_LA(ks + 1, (ks + 1) & 1)
            #pragma unroll
            for (int cf = 0; cf < 4; ++cf) {
                const int s = ks * 4 + cf, sl = s & 3;
                mf9(Ax0[ks & 1], Ax1[ks & 1], Ax2[ks & 1], Axv[ks & 1],
                    Bp[sl][0], Bp[sl][1], Bp[sl][2], P[cf], Q[cf], V[cf]);
                if (s + 4 < 16) D3_LB(s + 4, sl)
            }
        }
#undef D3_LA
#undef D3_LB
        #pragma unroll
        for (int cf = 0; cf < 4; ++cf) {
            int col = wave * 64 + cf * 16 + c16;
            float bb = bD3[cf];
            #pragma unroll
            for (int q = 0; q < 4; ++q) {
                int row = (lane >> 4) * 4 + q;
                float pre = P[cf][q] + Q[cf][q] + bb;
                xh[(size_t)(row0 + row) * IN_DIM + col] = fmaxf(pre, 0.f);
                dxh[(size_t)(row0 + row) * IN_DIM + col] = pre > 0.f ? V[cf][q] : 0.f;
            }
        }
    }
}

// =====================================================================
extern "C" void kernel_launch(void* const* d_in, const int* in_sizes, int n_in,
                              void* d_out, int out_size, void* d_ws, size_t ws_size,
                              hipStream_t stream)
{
    const float* x    = (const float*)d_in[0];
    const float* xdot = (const float*)d_in[1];
    const float* We1  = (const float*)d_in[2];
    const float* be1  = (const float*)d_in[3];
    const float* We2  = (const float*)d_in[4];
    const float* be2  = (const float*)d_in[5];
    const float* We3  = (const float*)d_in[6];
    const float* be3  = (const float*)d_in[7];
    const float* Wd1  = (const float*)d_in[8];
    const float* bd1  = (const float*)d_in[9];
    const float* Wd2  = (const float*)d_in[10];
    const float* bd2  = (const float*)d_in[11];
    const float* Wd3  = (const float*)d_in[12];
    const float* bd3  = (const float*)d_in[13];
    const float* XI   = (const float*)d_in[14];
    const float* XIm  = (const float*)d_in[15];

    float* out = (float*)d_out;
    float* xh  = out;
    float* dxh = out + (size_t)BATCH * IN_DIM;
    float* zo  = dxh + (size_t)BATCH * IN_DIM;
    float* dz  = zo + (size_t)BATCH * DDIM;
    float* dzs = dz + (size_t)BATCH * DDIM;

    int2*  pk  = (int2*)d_ws;
    short* Wp1 = (short*)(pk + NFPAD);
    short* Wp2 = Wp1 + 3 * WSZ1;
    short* Wp3 = Wp2 + 3 * WSZ2;
    short* Wp4 = Wp3 + 3 * WSZ3;
    short* Wp5 = Wp4 + 3 * WSZ4;
    short* Wp6 = Wp5 + 3 * WSZ5;
    short* xiP = Wp6 + 3 * WSZ6;

    initk<<<256, 256, 0, stream>>>(We1, We2, We3, Wd1, Wd2, Wd3, XI, XIm,
                                   Wp1, Wp2, Wp3, Wp4, Wp5, Wp6, xiP, pk);
    fused<<<BATCH / 16, 512, 0, stream>>>(x, xdot, be1, be2, be3, bd1, bd2, bd3,
                                          Wp1, Wp2, Wp3, Wp4, Wp5, Wp6, xiP, pk,
                                          xh, dxh, zo, dz, dzs);
}